// Round 1
// baseline (5771.915 us; speedup 1.0000x reference)
//
#include <hip/hip_runtime.h>
#include <math.h>

#define B_ 2
#define L_ 2048
#define E_ 2048
#define HQ 16
#define HKV 2
#define DH 128

// ---------------------------------------------------------------------------
// RoPE table: ctab[pos][f] = cos(pos * theta^(-f/64)), stab = sin, f in [0,64)
// ---------------------------------------------------------------------------
__global__ void rope_tab_kernel(float* __restrict__ ctab, float* __restrict__ stab) {
  int idx = blockIdx.x * 256 + threadIdx.x;
  if (idx >= L_ * (DH / 2)) return;
  int pos = idx >> 6;
  int f = idx & 63;
  float inv_freq = powf(10000.0f, -(float)f * (1.0f / 64.0f));
  float ang = (float)pos * inv_freq;
  float s, c;
  sincosf(ang, &s, &c);
  ctab[idx] = c;
  stab[idx] = s;
}

// ---------------------------------------------------------------------------
// RoPE apply, in place. buf layout: [(b*L+l)][H*128], rotate per head.
// idx = ((b*L+l)*H + h)*64 + f
// ---------------------------------------------------------------------------
__global__ void rope_apply_kernel(float* __restrict__ buf,
                                  const float* __restrict__ ctab,
                                  const float* __restrict__ stab,
                                  int H, int total) {
  int idx = blockIdx.x * 256 + threadIdx.x;
  if (idx >= total) return;
  int f = idx & 63;
  int row = idx >> 6;      // (b*L+l)*H + h
  int h = row % H;
  int bl = row / H;        // b*L + l
  int l = bl & (L_ - 1);
  size_t base = (size_t)bl * ((size_t)H * DH) + (size_t)h * DH;
  float x1 = buf[base + f];
  float x2 = buf[base + 64 + f];
  float c = ctab[l * 64 + f];
  float s = stab[l * 64 + f];
  buf[base + f]      = x1 * c - x2 * s;
  buf[base + 64 + f] = x2 * c + x1 * s;
}

// ---------------------------------------------------------------------------
// Tiled fp32 GEMM: C[M][N] = A[M][K] @ W[N][K]^T + bias[N]
// 64x64 tile, BK=32, 256 threads, 4x4 microtile per thread.
// ---------------------------------------------------------------------------
#define BM 64
#define BN 64
#define BK 32

__global__ __launch_bounds__(256) void gemm_nt_kernel(
    const float* __restrict__ A, const float* __restrict__ W,
    const float* __restrict__ bias, float* __restrict__ C,
    int M, int N, int K)
{
  __shared__ __align__(16) float As[BK][BM + 4];
  __shared__ __align__(16) float Ws[BK][BN + 4];
  const int tid = threadIdx.x;
  const int tx = tid & 15;
  const int ty = tid >> 4;
  const int bm = blockIdx.y * BM;
  const int bn = blockIdx.x * BN;

  float acc[4][4] = {};

  for (int k0 = 0; k0 < K; k0 += BK) {
#pragma unroll
    for (int rr = 0; rr < 2; ++rr) {
      int f = tid + 256 * rr;        // 0..511 float4 slots
      int row = f >> 3;              // 8 float4 per row of BK=32
      int c4 = (f & 7) * 4;
      float4 av = *reinterpret_cast<const float4*>(&A[(size_t)(bm + row) * K + k0 + c4]);
      As[c4 + 0][row] = av.x; As[c4 + 1][row] = av.y;
      As[c4 + 2][row] = av.z; As[c4 + 3][row] = av.w;
      float4 wv = *reinterpret_cast<const float4*>(&W[(size_t)(bn + row) * K + k0 + c4]);
      Ws[c4 + 0][row] = wv.x; Ws[c4 + 1][row] = wv.y;
      Ws[c4 + 2][row] = wv.z; Ws[c4 + 3][row] = wv.w;
    }
    __syncthreads();
#pragma unroll
    for (int kk = 0; kk < BK; ++kk) {
      float4 a4 = *reinterpret_cast<const float4*>(&As[kk][ty * 4]);
      float4 b4 = *reinterpret_cast<const float4*>(&Ws[kk][tx * 4]);
      float a[4] = {a4.x, a4.y, a4.z, a4.w};
      float b[4] = {b4.x, b4.y, b4.z, b4.w};
#pragma unroll
      for (int i = 0; i < 4; ++i)
#pragma unroll
        for (int j = 0; j < 4; ++j)
          acc[i][j] = fmaf(a[i], b[j], acc[i][j]);
    }
    __syncthreads();
  }

  float bv[4] = {0.f, 0.f, 0.f, 0.f};
  if (bias != nullptr) {
#pragma unroll
    for (int j = 0; j < 4; ++j) bv[j] = bias[bn + tx * 4 + j];
  }
#pragma unroll
  for (int i = 0; i < 4; ++i) {
    float4 r;
    r.x = acc[i][0] + bv[0];
    r.y = acc[i][1] + bv[1];
    r.z = acc[i][2] + bv[2];
    r.w = acc[i][3] + bv[3];
    *reinterpret_cast<float4*>(&C[(size_t)(bm + ty * 4 + i) * N + bn + tx * 4]) = r;
  }
}

// ---------------------------------------------------------------------------
// fp32 flash attention, causal, GQA. One wave per query row, 4 waves/block.
// q: [(b*L+l)][HQ*128] (pre-scaled? no - scale applied here)
// k,v: [(b*L+j)][HKV*128]
// o: [(b*L+l)][HQ*128]
// grid: (L/4, HQ, B)
// ---------------------------------------------------------------------------
__global__ __launch_bounds__(256) void flash_attn_f32_kernel(
    const float* __restrict__ q, const float* __restrict__ k,
    const float* __restrict__ v, float* __restrict__ o)
{
  const int wave = threadIdx.x >> 6;
  const int lane = threadIdx.x & 63;
  const int r = blockIdx.x * 4 + wave;
  const int h = blockIdx.y;
  const int b = blockIdx.z;
  const int kvh = h >> 3;   // G = HQ/HKV = 8
  const float scale = 0.08838834764831845f;  // 1/sqrt(128)
  const int d0 = lane * 2;

  size_t qbase = ((size_t)(b * L_ + r)) * (HQ * DH) + (size_t)h * DH + d0;
  float q0 = q[qbase] * scale;
  float q1 = q[qbase + 1] * scale;

  const float* kp = k + ((size_t)b * L_) * (HKV * DH) + (size_t)kvh * DH + d0;
  const float* vp = v + ((size_t)b * L_) * (HKV * DH) + (size_t)kvh * DH + d0;

  float m = -INFINITY;
  float l = 0.f;
  float o0 = 0.f, o1 = 0.f;

  for (int j = 0; j <= r; ++j) {
    float2 kk = *reinterpret_cast<const float2*>(&kp[(size_t)j * (HKV * DH)]);
    float part = q0 * kk.x + q1 * kk.y;
    part += __shfl_xor(part, 32);
    part += __shfl_xor(part, 16);
    part += __shfl_xor(part, 8);
    part += __shfl_xor(part, 4);
    part += __shfl_xor(part, 2);
    part += __shfl_xor(part, 1);
    float mn = fmaxf(m, part);
    float p = __expf(part - mn);
    float corr = __expf(m - mn);
    float2 vv = *reinterpret_cast<const float2*>(&vp[(size_t)j * (HKV * DH)]);
    l = l * corr + p;
    o0 = o0 * corr + p * vv.x;
    o1 = o1 * corr + p * vv.y;
    m = mn;
  }

  float inv = 1.0f / l;
  size_t ob = ((size_t)(b * L_ + r)) * (HQ * DH) + (size_t)h * DH + d0;
  o[ob] = o0 * inv;
  o[ob + 1] = o1 * inv;
}

// ---------------------------------------------------------------------------
// launch
// ---------------------------------------------------------------------------
extern "C" void kernel_launch(void* const* d_in, const int* in_sizes, int n_in,
                              void* d_out, int out_size, void* d_ws, size_t ws_size,
                              hipStream_t stream) {
  const float* x  = (const float*)d_in[0];
  const float* wq = (const float*)d_in[1];
  const float* wk = (const float*)d_in[2];
  const float* wv = (const float*)d_in[3];
  const float* wo = (const float*)d_in[4];
  const float* bq = (const float*)d_in[5];
  const float* bk = (const float*)d_in[6];
  const float* bv = (const float*)d_in[7];
  float* out = (float*)d_out;

  float* ws = (float*)d_ws;
  const size_t QN = (size_t)B_ * L_ * HQ * DH;    // 8388608
  const size_t KN = (size_t)B_ * L_ * HKV * DH;   // 1048576
  float* qb = ws;
  float* kb = qb + QN;
  float* vb = kb + KN;
  float* ab = vb + KN;
  float* ct = ab + QN;
  float* st = ct + (size_t)L_ * (DH / 2);

  const int M = B_ * L_;   // 4096

  // RoPE tables (no deps)
  rope_tab_kernel<<<(L_ * (DH / 2) + 255) / 256, 256, 0, stream>>>(ct, st);

  // Projections
  gemm_nt_kernel<<<dim3((HQ * DH) / BN, M / BM), 256, 0, stream>>>(
      x, wq, bq, qb, M, HQ * DH, E_);
  gemm_nt_kernel<<<dim3((HKV * DH) / BN, M / BM), 256, 0, stream>>>(
      x, wk, bk, kb, M, HKV * DH, E_);
  gemm_nt_kernel<<<dim3((HKV * DH) / BN, M / BM), 256, 0, stream>>>(
      x, wv, bv, vb, M, HKV * DH, E_);

  // RoPE
  {
    int totq = B_ * L_ * HQ * 64;
    rope_apply_kernel<<<(totq + 255) / 256, 256, 0, stream>>>(qb, ct, st, HQ, totq);
    int totk = B_ * L_ * HKV * 64;
    rope_apply_kernel<<<(totk + 255) / 256, 256, 0, stream>>>(kb, ct, st, HKV, totk);
  }

  // Attention
  flash_attn_f32_kernel<<<dim3(L_ / 4, HQ, B_), 256, 0, stream>>>(qb, kb, vb, ab);

  // Output projection (no bias)
  gemm_nt_kernel<<<dim3(E_ / BN, M / BM), 256, 0, stream>>>(
      ab, wo, nullptr, out, M, E_, E_);
}

// Round 2
// 1552.794 us; speedup vs baseline: 3.7171x; 3.7171x over previous
//
#include <hip/hip_runtime.h>
#include <math.h>

#define B_ 2
#define L_ 2048
#define E_ 2048
#define HQ 16
#define HKV 2
#define DH 128

typedef unsigned short u16;
typedef __attribute__((ext_vector_type(8))) short short8;
typedef __attribute__((ext_vector_type(4))) float f32x4;

static __device__ __forceinline__ u16 f2bf(float f) {
  unsigned int u = __float_as_uint(f);
  unsigned int r = (u + 0x7fffu + ((u >> 16) & 1u)) >> 16;
  return (u16)r;
}

// ---------------------------------------------------------------------------
// RoPE table: ctab[pos][f] = cos(pos * theta^(-f/64)), stab = sin
// ---------------------------------------------------------------------------
__global__ void rope_tab_kernel(float* __restrict__ ctab, float* __restrict__ stab) {
  int idx = blockIdx.x * 256 + threadIdx.x;
  if (idx >= L_ * (DH / 2)) return;
  int pos = idx >> 6;
  int f = idx & 63;
  float inv_freq = powf(10000.0f, -(float)f * (1.0f / 64.0f));
  float ang = (float)pos * inv_freq;
  float s, c;
  sincosf(ang, &s, &c);
  ctab[idx] = c;
  stab[idx] = s;
}

// ---------------------------------------------------------------------------
// RoPE apply + bf16 convert (+optional scale). in fp32 [(b*L+l)][H*128] ->
// out bf16 same layout.
// ---------------------------------------------------------------------------
__global__ void rope_convert_kernel(const float* __restrict__ in,
                                    u16* __restrict__ outb,
                                    const float* __restrict__ ctab,
                                    const float* __restrict__ stab,
                                    int H, float scale, int total) {
  int idx = blockIdx.x * 256 + threadIdx.x;
  if (idx >= total) return;
  int f = idx & 63;
  int row = idx >> 6;      // (b*L+l)*H + h
  int h = row % H;
  int bl = row / H;
  int l = bl & (L_ - 1);
  size_t base = (size_t)bl * ((size_t)H * DH) + (size_t)h * DH;
  float x1 = in[base + f];
  float x2 = in[base + 64 + f];
  float c = ctab[l * 64 + f];
  float s = stab[l * 64 + f];
  outb[base + f]      = f2bf((x1 * c - x2 * s) * scale);
  outb[base + 64 + f] = f2bf((x2 * c + x1 * s) * scale);
}

// ---------------------------------------------------------------------------
// V transpose + bf16 convert: V fp32 [(b*L+key)][kvh*128+d] ->
// Vt bf16 [(b*HKV+kvh)*128 + d][key]
// grid (L/64, DH/64, B*HKV), block 256
// ---------------------------------------------------------------------------
__global__ __launch_bounds__(256) void transpose_v_kernel(
    const float* __restrict__ v, u16* __restrict__ Vt) {
  __shared__ float tile[64][65];
  const int k0 = blockIdx.x * 64;
  const int d0 = blockIdx.y * 64;
  const int bk = blockIdx.z;          // b*HKV + kvh
  const int b = bk / HKV, kvh = bk % HKV;
#pragma unroll
  for (int i = 0; i < 4; ++i) {
    int key = i * 16 + (threadIdx.x >> 4);
    int d4 = (threadIdx.x & 15) * 4;
    float4 vv = *reinterpret_cast<const float4*>(
        &v[(size_t)(b * L_ + k0 + key) * (HKV * DH) + kvh * DH + d0 + d4]);
    tile[key][d4 + 0] = vv.x; tile[key][d4 + 1] = vv.y;
    tile[key][d4 + 2] = vv.z; tile[key][d4 + 3] = vv.w;
  }
  __syncthreads();
  const int d = threadIdx.x >> 2;
  const int kq = (threadIdx.x & 3) * 16;
  u16* orow = Vt + ((size_t)(bk * DH + d0 + d)) * L_ + k0 + kq;
#pragma unroll
  for (int j = 0; j < 16; ++j) orow[j] = f2bf(tile[kq + j][d]);
}

// ---------------------------------------------------------------------------
// Tiled fp32 GEMM: C[M][N] = A[M][K] @ W[N][K]^T + bias[N]
// ---------------------------------------------------------------------------
#define BM 64
#define BN 64
#define BK 32

__global__ __launch_bounds__(256) void gemm_nt_kernel(
    const float* __restrict__ A, const float* __restrict__ W,
    const float* __restrict__ bias, float* __restrict__ C,
    int M, int N, int K)
{
  __shared__ __align__(16) float As[BK][BM + 4];
  __shared__ __align__(16) float Ws[BK][BN + 4];
  const int tid = threadIdx.x;
  const int tx = tid & 15;
  const int ty = tid >> 4;
  const int bm = blockIdx.y * BM;
  const int bn = blockIdx.x * BN;

  float acc[4][4] = {};

  for (int k0 = 0; k0 < K; k0 += BK) {
#pragma unroll
    for (int rr = 0; rr < 2; ++rr) {
      int f = tid + 256 * rr;
      int row = f >> 3;
      int c4 = (f & 7) * 4;
      float4 av = *reinterpret_cast<const float4*>(&A[(size_t)(bm + row) * K + k0 + c4]);
      As[c4 + 0][row] = av.x; As[c4 + 1][row] = av.y;
      As[c4 + 2][row] = av.z; As[c4 + 3][row] = av.w;
      float4 wv = *reinterpret_cast<const float4*>(&W[(size_t)(bn + row) * K + k0 + c4]);
      Ws[c4 + 0][row] = wv.x; Ws[c4 + 1][row] = wv.y;
      Ws[c4 + 2][row] = wv.z; Ws[c4 + 3][row] = wv.w;
    }
    __syncthreads();
#pragma unroll
    for (int kk = 0; kk < BK; ++kk) {
      float4 a4 = *reinterpret_cast<const float4*>(&As[kk][ty * 4]);
      float4 b4 = *reinterpret_cast<const float4*>(&Ws[kk][tx * 4]);
      float a[4] = {a4.x, a4.y, a4.z, a4.w};
      float b[4] = {b4.x, b4.y, b4.z, b4.w};
#pragma unroll
      for (int i = 0; i < 4; ++i)
#pragma unroll
        for (int j = 0; j < 4; ++j)
          acc[i][j] = fmaf(a[i], b[j], acc[i][j]);
    }
    __syncthreads();
  }

  float bv[4] = {0.f, 0.f, 0.f, 0.f};
  if (bias != nullptr) {
#pragma unroll
    for (int j = 0; j < 4; ++j) bv[j] = bias[bn + tx * 4 + j];
  }
#pragma unroll
  for (int i = 0; i < 4; ++i) {
    float4 r;
    r.x = acc[i][0] + bv[0];
    r.y = acc[i][1] + bv[1];
    r.z = acc[i][2] + bv[2];
    r.w = acc[i][3] + bv[3];
    *reinterpret_cast<float4*>(&C[(size_t)(bm + ty * 4 + i) * N + bn + tx * 4]) = r;
  }
}

// ---------------------------------------------------------------------------
// bf16 MFMA flash attention, causal, GQA.
// One wave per 16-row Q tile; 4 waves/block; no inter-wave sync.
// Qb: [(b*L+l)][HQ*128] bf16 (RoPE + scale applied)
// Kb: [(b*L+k)][HKV*128] bf16 (RoPE applied)
// Vt: [(b*HKV+kvh)*128+d][key] bf16
// ab: [(b*L+l)][HQ*128] fp32
// grid (L/64, HQ, B), block 256
// ---------------------------------------------------------------------------
__global__ __launch_bounds__(256) void flash_attn_mfma_kernel(
    const u16* __restrict__ Qb, const u16* __restrict__ Kb,
    const u16* __restrict__ Vt, float* __restrict__ ab)
{
  const int wave = threadIdx.x >> 6;
  const int lane = threadIdx.x & 63;
  const int q0 = blockIdx.x * 64 + wave * 16;
  const int h = blockIdx.y;
  const int b = blockIdx.z;
  const int kvh = h >> 3;            // G = 8
  const int lr = lane & 15;          // A-row / B-col / C-col select
  const int lg = lane >> 4;          // k-group 0..3

  __shared__ u16 plds[4][16 * 40];   // P tile per wave, padded stride 40
  u16* pw = plds[wave];

  // Q fragments held in registers: qf[s][j] = Q[q0+lr][s*32 + lg*8 + j]
  const u16* qrow = Qb + ((size_t)(b * L_ + q0 + lr)) * (HQ * DH) + h * DH + lg * 8;
  short8 qf[4];
#pragma unroll
  for (int s = 0; s < 4; ++s)
    qf[s] = *reinterpret_cast<const short8*>(qrow + s * 32);

  const u16* kbase = Kb + ((size_t)(b * L_)) * (HKV * DH) + kvh * DH + lg * 8;
  const u16* vbase = Vt + ((size_t)((b * HKV + kvh) * DH)) * L_ + lg * 8;

  f32x4 O[8];
#pragma unroll
  for (int n = 0; n < 8; ++n) O[n] = (f32x4){0.f, 0.f, 0.f, 0.f};
  float mrun[4] = {-INFINITY, -INFINITY, -INFINITY, -INFINITY};
  float lrun[4] = {0.f, 0.f, 0.f, 0.f};

  const int jend = q0 + 16;
  for (int j0 = 0; j0 < jend; j0 += 32) {
    // ---- S = Q K^T for 2 key tiles of 16 ----
    f32x4 s0 = (f32x4){0.f, 0.f, 0.f, 0.f};
    f32x4 s1 = (f32x4){0.f, 0.f, 0.f, 0.f};
    const u16* k0p = kbase + (size_t)(j0 + lr) * (HKV * DH);
    const u16* k1p = k0p + (size_t)16 * (HKV * DH);
#pragma unroll
    for (int s = 0; s < 4; ++s) {
      short8 b0 = *reinterpret_cast<const short8*>(k0p + s * 32);
      short8 b1 = *reinterpret_cast<const short8*>(k1p + s * 32);
      s0 = __builtin_amdgcn_mfma_f32_16x16x32_bf16(qf[s], b0, s0, 0, 0, 0);
      s1 = __builtin_amdgcn_mfma_f32_16x16x32_bf16(qf[s], b1, s1, 0, 0, 0);
    }
    // ---- causal mask (boundary steps only) ----
    if (j0 + 31 > q0) {
      int key0 = j0 + lr;
#pragma unroll
      for (int r = 0; r < 4; ++r) {
        int q = q0 + lg * 4 + r;
        if (key0 > q)      s0[r] = -INFINITY;
        if (key0 + 16 > q) s1[r] = -INFINITY;
      }
    }
    // ---- row max over 32 keys (reduce across the 16-lane col group) ----
    float tmax[4];
#pragma unroll
    for (int r = 0; r < 4; ++r) tmax[r] = fmaxf(s0[r], s1[r]);
#pragma unroll
    for (int mm = 1; mm <= 8; mm <<= 1)
#pragma unroll
      for (int r = 0; r < 4; ++r) tmax[r] = fmaxf(tmax[r], __shfl_xor(tmax[r], mm));
    float corr[4];
#pragma unroll
    for (int r = 0; r < 4; ++r) {
      float mn = fmaxf(mrun[r], tmax[r]);
      corr[r] = __expf(mrun[r] - mn);
      mrun[r] = mn;
    }
    // ---- P = exp(S - m), row sum ----
    float p0[4], p1[4], rs[4];
#pragma unroll
    for (int r = 0; r < 4; ++r) {
      p0[r] = __expf(s0[r] - mrun[r]);
      p1[r] = __expf(s1[r] - mrun[r]);
      rs[r] = p0[r] + p1[r];
    }
#pragma unroll
    for (int mm = 1; mm <= 8; mm <<= 1)
#pragma unroll
      for (int r = 0; r < 4; ++r) rs[r] += __shfl_xor(rs[r], mm);
#pragma unroll
    for (int r = 0; r < 4; ++r) lrun[r] = lrun[r] * corr[r] + rs[r];
    // ---- rescale O ----
#pragma unroll
    for (int n = 0; n < 8; ++n)
#pragma unroll
      for (int r = 0; r < 4; ++r) O[n][r] *= corr[r];
    // ---- P -> LDS (bf16), reshape to A-fragment layout ----
#pragma unroll
    for (int r = 0; r < 4; ++r) {
      pw[(lg * 4 + r) * 40 + lr]      = f2bf(p0[r]);
      pw[(lg * 4 + r) * 40 + 16 + lr] = f2bf(p1[r]);
    }
    short8 pa = *reinterpret_cast<const short8*>(&pw[lr * 40 + lg * 8]);
    // ---- O += P V ----
    const u16* vp = vbase + j0;
#pragma unroll
    for (int n = 0; n < 8; ++n) {
      short8 bv = *reinterpret_cast<const short8*>(vp + (size_t)(n * 16 + lr) * L_);
      O[n] = __builtin_amdgcn_mfma_f32_16x16x32_bf16(pa, bv, O[n], 0, 0, 0);
    }
  }

  // ---- epilogue ----
  float inv[4];
#pragma unroll
  for (int r = 0; r < 4; ++r) inv[r] = 1.0f / lrun[r];
  float* obase = ab + (size_t)(b * L_ + q0) * (HQ * DH) + h * DH;
#pragma unroll
  for (int n = 0; n < 8; ++n)
#pragma unroll
    for (int r = 0; r < 4; ++r)
      obase[(size_t)(lg * 4 + r) * (HQ * DH) + n * 16 + lr] = O[n][r] * inv[r];
}

// ---------------------------------------------------------------------------
// launch
// ---------------------------------------------------------------------------
extern "C" void kernel_launch(void* const* d_in, const int* in_sizes, int n_in,
                              void* d_out, int out_size, void* d_ws, size_t ws_size,
                              hipStream_t stream) {
  const float* x  = (const float*)d_in[0];
  const float* wq = (const float*)d_in[1];
  const float* wk = (const float*)d_in[2];
  const float* wv = (const float*)d_in[3];
  const float* wo = (const float*)d_in[4];
  const float* bq = (const float*)d_in[5];
  const float* bk = (const float*)d_in[6];
  const float* bv = (const float*)d_in[7];
  float* out = (float*)d_out;

  float* ws = (float*)d_ws;
  const size_t QN = (size_t)B_ * L_ * HQ * DH;    // 8388608
  const size_t KN = (size_t)B_ * L_ * HKV * DH;   // 1048576
  const size_t TN = (size_t)L_ * (DH / 2);        // 131072

  float* qb = ws;            // fp32 q proj (later reused as attn out `ab`)
  float* kb = qb + QN;
  float* vb = kb + KN;
  float* ct = vb + KN;
  float* st = ct + TN;
  u16* Qbf = (u16*)(st + TN);
  u16* Kbf = Qbf + QN;
  u16* Vt  = Kbf + KN;
  float* ab = qb;            // alias: qb dead after rope_convert

  const int M = B_ * L_;     // 4096
  const float scale = 0.08838834764831845f;  // 1/sqrt(128)

  rope_tab_kernel<<<(L_ * (DH / 2) + 255) / 256, 256, 0, stream>>>(ct, st);

  gemm_nt_kernel<<<dim3((HQ * DH) / BN, M / BM), 256, 0, stream>>>(
      x, wq, bq, qb, M, HQ * DH, E_);
  gemm_nt_kernel<<<dim3((HKV * DH) / BN, M / BM), 256, 0, stream>>>(
      x, wk, bk, kb, M, HKV * DH, E_);
  gemm_nt_kernel<<<dim3((HKV * DH) / BN, M / BM), 256, 0, stream>>>(
      x, wv, bv, vb, M, HKV * DH, E_);

  {
    int totq = B_ * L_ * HQ * 64;
    rope_convert_kernel<<<(totq + 255) / 256, 256, 0, stream>>>(
        qb, Qbf, ct, st, HQ, scale, totq);
    int totk = B_ * L_ * HKV * 64;
    rope_convert_kernel<<<(totk + 255) / 256, 256, 0, stream>>>(
        kb, Kbf, ct, st, HKV, 1.0f, totk);
  }
  transpose_v_kernel<<<dim3(L_ / 64, DH / 64, B_ * HKV), 256, 0, stream>>>(vb, Vt);

  flash_attn_mfma_kernel<<<dim3(L_ / 64, HQ, B_), 256, 0, stream>>>(
      Qbf, Kbf, Vt, ab);

  gemm_nt_kernel<<<dim3(E_ / BN, M / BM), 256, 0, stream>>>(
      ab, wo, nullptr, out, M, E_, E_);
}

// Round 3
// 654.045 us; speedup vs baseline: 8.8250x; 2.3741x over previous
//
#include <hip/hip_runtime.h>
#include <math.h>

#define B_ 2
#define L_ 2048
#define E_ 2048
#define HQ 16
#define HKV 2
#define DH 128

typedef unsigned short u16;
typedef __attribute__((ext_vector_type(8))) short short8;
typedef __attribute__((ext_vector_type(4))) float f32x4;

static __device__ __forceinline__ u16 f2bf(float f) {
  unsigned int u = __float_as_uint(f);
  unsigned int r = (u + 0x7fffu + ((u >> 16) & 1u)) >> 16;
  return (u16)r;
}

#define GLB(p) ((const __attribute__((address_space(1))) void*)(p))
#define LDS(p) ((__attribute__((address_space(3))) void*)(p))

// ---------------------------------------------------------------------------
// fp32 -> bf16 convert, 8 elems/thread. n must be divisible by 8.
// ---------------------------------------------------------------------------
__global__ void cvt_bf16_kernel(const float* __restrict__ in,
                                u16* __restrict__ out, int n) {
  int i = (blockIdx.x * 256 + threadIdx.x) * 8;
  if (i >= n) return;
  float4 a = *reinterpret_cast<const float4*>(in + i);
  float4 b = *reinterpret_cast<const float4*>(in + i + 4);
  short8 r;
  r[0] = (short)f2bf(a.x); r[1] = (short)f2bf(a.y);
  r[2] = (short)f2bf(a.z); r[3] = (short)f2bf(a.w);
  r[4] = (short)f2bf(b.x); r[5] = (short)f2bf(b.y);
  r[6] = (short)f2bf(b.z); r[7] = (short)f2bf(b.w);
  *reinterpret_cast<short8*>(out + i) = r;
}

// ---------------------------------------------------------------------------
// RoPE table
// ---------------------------------------------------------------------------
__global__ void rope_tab_kernel(float* __restrict__ ctab, float* __restrict__ stab) {
  int idx = blockIdx.x * 256 + threadIdx.x;
  if (idx >= L_ * (DH / 2)) return;
  int pos = idx >> 6;
  int f = idx & 63;
  float inv_freq = powf(10000.0f, -(float)f * (1.0f / 64.0f));
  float ang = (float)pos * inv_freq;
  float s, c;
  sincosf(ang, &s, &c);
  ctab[idx] = c;
  stab[idx] = s;
}

// ---------------------------------------------------------------------------
// RoPE apply + bf16 convert from qkv buffer.
// src row = (b*L+l), stride rowStride, col colOff + h*DH + d
// dst bf16 [(b*L+l)][H*128]
// ---------------------------------------------------------------------------
__global__ void rope_convert_kernel(const float* __restrict__ in,
                                    u16* __restrict__ outb,
                                    const float* __restrict__ ctab,
                                    const float* __restrict__ stab,
                                    int H, int rowStride, int colOff,
                                    float scale, int total) {
  int idx = blockIdx.x * 256 + threadIdx.x;
  if (idx >= total) return;
  int f = idx & 63;
  int row = idx >> 6;      // (b*L+l)*H + h
  int h = row % H;
  int bl = row / H;
  int l = bl & (L_ - 1);
  size_t sbase = (size_t)bl * rowStride + colOff + (size_t)h * DH;
  size_t dbase = (size_t)bl * ((size_t)H * DH) + (size_t)h * DH;
  float x1 = in[sbase + f];
  float x2 = in[sbase + 64 + f];
  float c = ctab[l * 64 + f];
  float s = stab[l * 64 + f];
  outb[dbase + f]      = f2bf((x1 * c - x2 * s) * scale);
  outb[dbase + 64 + f] = f2bf((x2 * c + x1 * s) * scale);
}

// ---------------------------------------------------------------------------
// V transpose + bf16 convert from qkv buffer:
// src [(b*L+key)][rowStride] at colOff + kvh*128 + d -> Vt [(b*HKV+kvh)*128+d][key]
// grid (L/64, DH/64, B*HKV), block 256
// ---------------------------------------------------------------------------
__global__ __launch_bounds__(256) void transpose_v_kernel(
    const float* __restrict__ v, u16* __restrict__ Vt,
    int rowStride, int colOff) {
  __shared__ float tile[64][65];
  const int k0 = blockIdx.x * 64;
  const int d0 = blockIdx.y * 64;
  const int bk = blockIdx.z;          // b*HKV + kvh
  const int b = bk / HKV, kvh = bk % HKV;
#pragma unroll
  for (int i = 0; i < 4; ++i) {
    int key = i * 16 + (threadIdx.x >> 4);
    int d4 = (threadIdx.x & 15) * 4;
    float4 vv = *reinterpret_cast<const float4*>(
        &v[(size_t)(b * L_ + k0 + key) * rowStride + colOff + kvh * DH + d0 + d4]);
    tile[key][d4 + 0] = vv.x; tile[key][d4 + 1] = vv.y;
    tile[key][d4 + 2] = vv.z; tile[key][d4 + 3] = vv.w;
  }
  __syncthreads();
  const int d = threadIdx.x >> 2;
  const int kq = (threadIdx.x & 3) * 16;
  u16* orow = Vt + ((size_t)(bk * DH + d0 + d)) * L_ + k0 + kq;
#pragma unroll
  for (int j = 0; j < 16; ++j) orow[j] = f2bf(tile[kq + j][d]);
}

// ---------------------------------------------------------------------------
// bf16 MFMA GEMM (m97 structure): C[M][N] = A[M][K] @ W[N][K]^T + bias
// A,W bf16; C fp32. 128x128 tile, BK=32, 256 threads (4 waves 2x2),
// global_load_lds width-16 staging, 16 MFMA per K-step.
// ---------------------------------------------------------------------------
#define GBM 128
#define GBN 128
#define GBK 32

__global__ __launch_bounds__(256) void gemm_bf16_kernel(
    const u16* __restrict__ A, const u16* __restrict__ W,
    const float* __restrict__ bias, float* __restrict__ C,
    int M, int N, int K)
{
  __shared__ u16 As[GBM][GBK];   // 8 KB
  __shared__ u16 Bs[GBN][GBK];   // 8 KB
  const int tid = threadIdx.x;
  const int wave = tid >> 6;
  const int lane = tid & 63;
  const int lr = lane & 15;
  const int lg = lane >> 4;
  const int bm = blockIdx.y * GBM;
  const int bn = blockIdx.x * GBN;
  const int wm = (wave >> 1) * 64;
  const int wn = (wave & 1) * 64;

  // staging: lane covers row srow (+64 for issue 1), 8 bf16 at scol
  const int srow = wave * 16 + (lane >> 2);
  const int scol = (lane & 3) * 8;
  const u16* ga = A + (size_t)(bm + srow) * K + scol;
  const u16* gb = W + (size_t)(bn + srow) * K + scol;
  u16* lA0 = &As[wave * 16][0];
  u16* lA1 = &As[64 + wave * 16][0];
  u16* lB0 = &Bs[wave * 16][0];
  u16* lB1 = &Bs[64 + wave * 16][0];

  f32x4 acc[4][4];
#pragma unroll
  for (int i = 0; i < 4; ++i)
#pragma unroll
    for (int j = 0; j < 4; ++j) acc[i][j] = (f32x4){0.f, 0.f, 0.f, 0.f};

  for (int k0 = 0; k0 < K; k0 += GBK) {
    __syncthreads();   // previous compute done before overwrite
    __builtin_amdgcn_global_load_lds(GLB(ga + k0), LDS(lA0), 16, 0, 0);
    __builtin_amdgcn_global_load_lds(GLB(ga + k0 + (size_t)64 * K), LDS(lA1), 16, 0, 0);
    __builtin_amdgcn_global_load_lds(GLB(gb + k0), LDS(lB0), 16, 0, 0);
    __builtin_amdgcn_global_load_lds(GLB(gb + k0 + (size_t)64 * K), LDS(lB1), 16, 0, 0);
    __syncthreads();   // loads landed

    short8 af[4], bf[4];
#pragma unroll
    for (int mi = 0; mi < 4; ++mi)
      af[mi] = *reinterpret_cast<const short8*>(&As[wm + mi * 16 + lr][lg * 8]);
#pragma unroll
    for (int ni = 0; ni < 4; ++ni)
      bf[ni] = *reinterpret_cast<const short8*>(&Bs[wn + ni * 16 + lr][lg * 8]);
#pragma unroll
    for (int mi = 0; mi < 4; ++mi)
#pragma unroll
      for (int ni = 0; ni < 4; ++ni)
        acc[mi][ni] = __builtin_amdgcn_mfma_f32_16x16x32_bf16(af[mi], bf[ni], acc[mi][ni], 0, 0, 0);
  }

  // epilogue: C[row = bm+wm+mi*16+lg*4+r][col = bn+wn+ni*16+lr]
#pragma unroll
  for (int ni = 0; ni < 4; ++ni) {
    int col = bn + wn + ni * 16 + lr;
    float bv = (bias != nullptr) ? bias[col] : 0.f;
#pragma unroll
    for (int mi = 0; mi < 4; ++mi) {
#pragma unroll
      for (int r = 0; r < 4; ++r) {
        int row = bm + wm + mi * 16 + lg * 4 + r;
        C[(size_t)row * N + col] = acc[mi][ni][r] + bv;
      }
    }
  }
}

// ---------------------------------------------------------------------------
// bf16 MFMA flash attention, causal, GQA. Output bf16.
// grid (L/64, HQ, B), block 256 (4 indep waves, 16 q-rows each)
// ---------------------------------------------------------------------------
__global__ __launch_bounds__(256) void flash_attn_mfma_kernel(
    const u16* __restrict__ Qb, const u16* __restrict__ Kb,
    const u16* __restrict__ Vt, u16* __restrict__ ab)
{
  const int wave = threadIdx.x >> 6;
  const int lane = threadIdx.x & 63;
  const int q0 = blockIdx.x * 64 + wave * 16;
  const int h = blockIdx.y;
  const int b = blockIdx.z;
  const int kvh = h >> 3;            // G = 8
  const int lr = lane & 15;
  const int lg = lane >> 4;

  __shared__ u16 plds[4][16 * 40];
  u16* pw = plds[wave];

  const u16* qrow = Qb + ((size_t)(b * L_ + q0 + lr)) * (HQ * DH) + h * DH + lg * 8;
  short8 qf[4];
#pragma unroll
  for (int s = 0; s < 4; ++s)
    qf[s] = *reinterpret_cast<const short8*>(qrow + s * 32);

  const u16* kbase = Kb + ((size_t)(b * L_)) * (HKV * DH) + kvh * DH + lg * 8;
  const u16* vbase = Vt + ((size_t)((b * HKV + kvh) * DH)) * L_ + lg * 8;

  f32x4 O[8];
#pragma unroll
  for (int n = 0; n < 8; ++n) O[n] = (f32x4){0.f, 0.f, 0.f, 0.f};
  float mrun[4] = {-INFINITY, -INFINITY, -INFINITY, -INFINITY};
  float lrun[4] = {0.f, 0.f, 0.f, 0.f};

  const int jend = q0 + 16;
  for (int j0 = 0; j0 < jend; j0 += 32) {
    f32x4 s0 = (f32x4){0.f, 0.f, 0.f, 0.f};
    f32x4 s1 = (f32x4){0.f, 0.f, 0.f, 0.f};
    const u16* k0p = kbase + (size_t)(j0 + lr) * (HKV * DH);
    const u16* k1p = k0p + (size_t)16 * (HKV * DH);
#pragma unroll
    for (int s = 0; s < 4; ++s) {
      short8 b0 = *reinterpret_cast<const short8*>(k0p + s * 32);
      short8 b1 = *reinterpret_cast<const short8*>(k1p + s * 32);
      s0 = __builtin_amdgcn_mfma_f32_16x16x32_bf16(qf[s], b0, s0, 0, 0, 0);
      s1 = __builtin_amdgcn_mfma_f32_16x16x32_bf16(qf[s], b1, s1, 0, 0, 0);
    }
    if (j0 + 31 > q0) {
      int key0 = j0 + lr;
#pragma unroll
      for (int r = 0; r < 4; ++r) {
        int q = q0 + lg * 4 + r;
        if (key0 > q)      s0[r] = -INFINITY;
        if (key0 + 16 > q) s1[r] = -INFINITY;
      }
    }
    float tmax[4];
#pragma unroll
    for (int r = 0; r < 4; ++r) tmax[r] = fmaxf(s0[r], s1[r]);
#pragma unroll
    for (int mm = 1; mm <= 8; mm <<= 1)
#pragma unroll
      for (int r = 0; r < 4; ++r) tmax[r] = fmaxf(tmax[r], __shfl_xor(tmax[r], mm));
    float corr[4];
#pragma unroll
    for (int r = 0; r < 4; ++r) {
      float mn = fmaxf(mrun[r], tmax[r]);
      corr[r] = __expf(mrun[r] - mn);
      mrun[r] = mn;
    }
    float p0[4], p1[4], rs[4];
#pragma unroll
    for (int r = 0; r < 4; ++r) {
      p0[r] = __expf(s0[r] - mrun[r]);
      p1[r] = __expf(s1[r] - mrun[r]);
      rs[r] = p0[r] + p1[r];
    }
#pragma unroll
    for (int mm = 1; mm <= 8; mm <<= 1)
#pragma unroll
      for (int r = 0; r < 4; ++r) rs[r] += __shfl_xor(rs[r], mm);
#pragma unroll
    for (int r = 0; r < 4; ++r) lrun[r] = lrun[r] * corr[r] + rs[r];
#pragma unroll
    for (int n = 0; n < 8; ++n)
#pragma unroll
      for (int r = 0; r < 4; ++r) O[n][r] *= corr[r];
#pragma unroll
    for (int r = 0; r < 4; ++r) {
      pw[(lg * 4 + r) * 40 + lr]      = f2bf(p0[r]);
      pw[(lg * 4 + r) * 40 + 16 + lr] = f2bf(p1[r]);
    }
    short8 pa = *reinterpret_cast<const short8*>(&pw[lr * 40 + lg * 8]);
    const u16* vp = vbase + j0;
#pragma unroll
    for (int n = 0; n < 8; ++n) {
      short8 bv = *reinterpret_cast<const short8*>(vp + (size_t)(n * 16 + lr) * L_);
      O[n] = __builtin_amdgcn_mfma_f32_16x16x32_bf16(pa, bv, O[n], 0, 0, 0);
    }
  }

  float inv[4];
#pragma unroll
  for (int r = 0; r < 4; ++r) inv[r] = 1.0f / lrun[r];
  u16* obase = ab + (size_t)(b * L_ + q0) * (HQ * DH) + h * DH;
#pragma unroll
  for (int n = 0; n < 8; ++n)
#pragma unroll
    for (int r = 0; r < 4; ++r)
      obase[(size_t)(lg * 4 + r) * (HQ * DH) + n * 16 + lr] = f2bf(O[n][r] * inv[r]);
}

// ---------------------------------------------------------------------------
// launch
// ---------------------------------------------------------------------------
extern "C" void kernel_launch(void* const* d_in, const int* in_sizes, int n_in,
                              void* d_out, int out_size, void* d_ws, size_t ws_size,
                              hipStream_t stream) {
  const float* x  = (const float*)d_in[0];
  const float* wq = (const float*)d_in[1];
  const float* wk = (const float*)d_in[2];
  const float* wv = (const float*)d_in[3];
  const float* wo = (const float*)d_in[4];
  const float* bq = (const float*)d_in[5];
  const float* bk = (const float*)d_in[6];
  const float* bv = (const float*)d_in[7];
  float* out = (float*)d_out;

  const int M = B_ * L_;        // 4096
  const int NQKV = HQ * DH + 2 * HKV * DH;  // 2048 + 512 = 2560
  const size_t QN = (size_t)B_ * L_ * HQ * DH;    // 8388608
  const size_t KN = (size_t)B_ * L_ * HKV * DH;   // 1048576
  const size_t TN = (size_t)L_ * (DH / 2);        // 131072

  float* ws = (float*)d_ws;
  float* qkvf = ws;                          // 4096*2560 f32 = 10485760
  float* ct   = qkvf + (size_t)M * NQKV;
  float* st   = ct + TN;
  float* bqkv = st + TN;                     // 2560 f32
  u16* xb     = (u16*)(bqkv + 2560);         // 8388608 u16
  u16* wqkvb  = xb + (size_t)M * E_;         // 2560*2048 u16
  u16* Qbf    = wqkvb + (size_t)NQKV * E_;   // 8388608 u16
  u16* Kbf    = Qbf + QN;                    // 1048576 u16
  u16* Vt     = Kbf + KN;                    // 1048576 u16
  u16* ab     = (u16*)qkvf;                  // alias: qkvf dead after rope/transpose
  u16* wob    = Qbf;                         // alias: Qbf dead after attention

  const float scale = 0.08838834764831845f;  // 1/sqrt(128)

  rope_tab_kernel<<<(L_ * (DH / 2) + 255) / 256, 256, 0, stream>>>(ct, st);

  // converts
  cvt_bf16_kernel<<<(int)(QN / 8 / 256), 256, 0, stream>>>(x, xb, (int)QN);
  cvt_bf16_kernel<<<(HQ * DH * E_) / 8 / 256, 256, 0, stream>>>(wq, wqkvb, HQ * DH * E_);
  cvt_bf16_kernel<<<(HKV * DH * E_) / 8 / 256, 256, 0, stream>>>(
      wk, wqkvb + (size_t)(HQ * DH) * E_, HKV * DH * E_);
  cvt_bf16_kernel<<<(HKV * DH * E_) / 8 / 256, 256, 0, stream>>>(
      wv, wqkvb + (size_t)(HQ * DH + HKV * DH) * E_, HKV * DH * E_);

  // bias concat
  hipMemcpyAsync(bqkv, bq, (size_t)HQ * DH * 4, hipMemcpyDeviceToDevice, stream);
  hipMemcpyAsync(bqkv + HQ * DH, bk, (size_t)HKV * DH * 4, hipMemcpyDeviceToDevice, stream);
  hipMemcpyAsync(bqkv + HQ * DH + HKV * DH, bv, (size_t)HKV * DH * 4, hipMemcpyDeviceToDevice, stream);

  // fused QKV projection: [4096][2560]
  gemm_bf16_kernel<<<dim3(NQKV / GBN, M / GBM), 256, 0, stream>>>(
      xb, wqkvb, bqkv, qkvf, M, NQKV, E_);

  // RoPE + convert
  {
    int totq = B_ * L_ * HQ * 64;
    rope_convert_kernel<<<(totq + 255) / 256, 256, 0, stream>>>(
        qkvf, Qbf, ct, st, HQ, NQKV, 0, scale, totq);
    int totk = B_ * L_ * HKV * 64;
    rope_convert_kernel<<<(totk + 255) / 256, 256, 0, stream>>>(
        qkvf, Kbf, ct, st, HKV, NQKV, HQ * DH, 1.0f, totk);
  }
  transpose_v_kernel<<<dim3(L_ / 64, DH / 64, B_ * HKV), 256, 0, stream>>>(
      qkvf, Vt, NQKV, HQ * DH + HKV * DH);

  // attention (writes bf16 ab, aliasing qkvf)
  flash_attn_mfma_kernel<<<dim3(L_ / 64, HQ, B_), 256, 0, stream>>>(
      Qbf, Kbf, Vt, ab);

  // wo convert (into dead Qbf region), then O-projection
  cvt_bf16_kernel<<<(E_ * E_) / 8 / 256, 256, 0, stream>>>(wo, wob, E_ * E_);
  gemm_bf16_kernel<<<dim3(E_ / GBN, M / GBM), 256, 0, stream>>>(
      ab, wob, nullptr, out, M, E_, E_);
}

// Round 4
// 399.402 us; speedup vs baseline: 14.4514x; 1.6376x over previous
//
#include <hip/hip_runtime.h>
#include <math.h>

#define B_ 2
#define L_ 2048
#define E_ 2048
#define HQ 16
#define HKV 2
#define DH 128

typedef unsigned short u16;
typedef __attribute__((ext_vector_type(8))) short short8;
typedef __attribute__((ext_vector_type(4))) float f32x4;

static __device__ __forceinline__ u16 f2bf(float f) {
  unsigned int u = __float_as_uint(f);
  unsigned int r = (u + 0x7fffu + ((u >> 16) & 1u)) >> 16;
  return (u16)r;
}

#define GLB(p) ((const __attribute__((address_space(1))) void*)(p))
#define LDS(p) ((__attribute__((address_space(3))) void*)(p))

// ---------------------------------------------------------------------------
// fp32 -> bf16 convert
// ---------------------------------------------------------------------------
__global__ void cvt_bf16_kernel(const float* __restrict__ in,
                                u16* __restrict__ out, int n) {
  int i = (blockIdx.x * 256 + threadIdx.x) * 8;
  if (i >= n) return;
  float4 a = *reinterpret_cast<const float4*>(in + i);
  float4 b = *reinterpret_cast<const float4*>(in + i + 4);
  short8 r;
  r[0] = (short)f2bf(a.x); r[1] = (short)f2bf(a.y);
  r[2] = (short)f2bf(a.z); r[3] = (short)f2bf(a.w);
  r[4] = (short)f2bf(b.x); r[5] = (short)f2bf(b.y);
  r[6] = (short)f2bf(b.z); r[7] = (short)f2bf(b.w);
  *reinterpret_cast<short8*>(out + i) = r;
}

// ---------------------------------------------------------------------------
// RoPE table
// ---------------------------------------------------------------------------
__global__ void rope_tab_kernel(float* __restrict__ ctab, float* __restrict__ stab) {
  int idx = blockIdx.x * 256 + threadIdx.x;
  if (idx >= L_ * (DH / 2)) return;
  int pos = idx >> 6;
  int f = idx & 63;
  float inv_freq = powf(10000.0f, -(float)f * (1.0f / 64.0f));
  float ang = (float)pos * inv_freq;
  float s, c;
  sincosf(ang, &s, &c);
  ctab[idx] = c;
  stab[idx] = s;
}

// ---------------------------------------------------------------------------
// RoPE apply + bf16 convert from qkv buffer.
// ---------------------------------------------------------------------------
__global__ void rope_convert_kernel(const float* __restrict__ in,
                                    u16* __restrict__ outb,
                                    const float* __restrict__ ctab,
                                    const float* __restrict__ stab,
                                    int H, int rowStride, int colOff,
                                    float scale, int total) {
  int idx = blockIdx.x * 256 + threadIdx.x;
  if (idx >= total) return;
  int f = idx & 63;
  int row = idx >> 6;
  int h = row % H;
  int bl = row / H;
  int l = bl & (L_ - 1);
  size_t sbase = (size_t)bl * rowStride + colOff + (size_t)h * DH;
  size_t dbase = (size_t)bl * ((size_t)H * DH) + (size_t)h * DH;
  float x1 = in[sbase + f];
  float x2 = in[sbase + 64 + f];
  float c = ctab[l * 64 + f];
  float s = stab[l * 64 + f];
  outb[dbase + f]      = f2bf((x1 * c - x2 * s) * scale);
  outb[dbase + 64 + f] = f2bf((x2 * c + x1 * s) * scale);
}

// ---------------------------------------------------------------------------
// V transpose + bf16 convert
// ---------------------------------------------------------------------------
__global__ __launch_bounds__(256) void transpose_v_kernel(
    const float* __restrict__ v, u16* __restrict__ Vt,
    int rowStride, int colOff) {
  __shared__ float tile[64][65];
  const int k0 = blockIdx.x * 64;
  const int d0 = blockIdx.y * 64;
  const int bk = blockIdx.z;
  const int b = bk / HKV, kvh = bk % HKV;
#pragma unroll
  for (int i = 0; i < 4; ++i) {
    int key = i * 16 + (threadIdx.x >> 4);
    int d4 = (threadIdx.x & 15) * 4;
    float4 vv = *reinterpret_cast<const float4*>(
        &v[(size_t)(b * L_ + k0 + key) * rowStride + colOff + kvh * DH + d0 + d4]);
    tile[key][d4 + 0] = vv.x; tile[key][d4 + 1] = vv.y;
    tile[key][d4 + 2] = vv.z; tile[key][d4 + 3] = vv.w;
  }
  __syncthreads();
  const int d = threadIdx.x >> 2;
  const int kq = (threadIdx.x & 3) * 16;
  u16* orow = Vt + ((size_t)(bk * DH + d0 + d)) * L_ + k0 + kq;
#pragma unroll
  for (int j = 0; j < 16; ++j) orow[j] = f2bf(tile[kq + j][d]);
}

// ---------------------------------------------------------------------------
// bf16 MFMA GEMM (m97 structure)
// ---------------------------------------------------------------------------
#define GBM 128
#define GBN 128
#define GBK 32

__global__ __launch_bounds__(256) void gemm_bf16_kernel(
    const u16* __restrict__ A, const u16* __restrict__ W,
    const float* __restrict__ bias, float* __restrict__ C,
    int M, int N, int K)
{
  __shared__ u16 As[GBM][GBK];
  __shared__ u16 Bs[GBN][GBK];
  const int tid = threadIdx.x;
  const int wave = tid >> 6;
  const int lane = tid & 63;
  const int lr = lane & 15;
  const int lg = lane >> 4;
  const int bm = blockIdx.y * GBM;
  const int bn = blockIdx.x * GBN;
  const int wm = (wave >> 1) * 64;
  const int wn = (wave & 1) * 64;

  const int srow = wave * 16 + (lane >> 2);
  const int scol = (lane & 3) * 8;
  const u16* ga = A + (size_t)(bm + srow) * K + scol;
  const u16* gb = W + (size_t)(bn + srow) * K + scol;
  u16* lA0 = &As[wave * 16][0];
  u16* lA1 = &As[64 + wave * 16][0];
  u16* lB0 = &Bs[wave * 16][0];
  u16* lB1 = &Bs[64 + wave * 16][0];

  f32x4 acc[4][4];
#pragma unroll
  for (int i = 0; i < 4; ++i)
#pragma unroll
    for (int j = 0; j < 4; ++j) acc[i][j] = (f32x4){0.f, 0.f, 0.f, 0.f};

  for (int k0 = 0; k0 < K; k0 += GBK) {
    __syncthreads();
    __builtin_amdgcn_global_load_lds(GLB(ga + k0), LDS(lA0), 16, 0, 0);
    __builtin_amdgcn_global_load_lds(GLB(ga + k0 + (size_t)64 * K), LDS(lA1), 16, 0, 0);
    __builtin_amdgcn_global_load_lds(GLB(gb + k0), LDS(lB0), 16, 0, 0);
    __builtin_amdgcn_global_load_lds(GLB(gb + k0 + (size_t)64 * K), LDS(lB1), 16, 0, 0);
    __syncthreads();

    short8 af[4], bf[4];
#pragma unroll
    for (int mi = 0; mi < 4; ++mi)
      af[mi] = *reinterpret_cast<const short8*>(&As[wm + mi * 16 + lr][lg * 8]);
#pragma unroll
    for (int ni = 0; ni < 4; ++ni)
      bf[ni] = *reinterpret_cast<const short8*>(&Bs[wn + ni * 16 + lr][lg * 8]);
#pragma unroll
    for (int mi = 0; mi < 4; ++mi)
#pragma unroll
      for (int ni = 0; ni < 4; ++ni)
        acc[mi][ni] = __builtin_amdgcn_mfma_f32_16x16x32_bf16(af[mi], bf[ni], acc[mi][ni], 0, 0, 0);
  }

#pragma unroll
  for (int ni = 0; ni < 4; ++ni) {
    int col = bn + wn + ni * 16 + lr;
    float bv = (bias != nullptr) ? bias[col] : 0.f;
#pragma unroll
    for (int mi = 0; mi < 4; ++mi) {
#pragma unroll
      for (int r = 0; r < 4; ++r) {
        int row = bm + wm + mi * 16 + lg * 4 + r;
        C[(size_t)row * N + col] = acc[mi][ni][r] + bv;
      }
    }
  }
}

// ---------------------------------------------------------------------------
// bf16 MFMA flash attention, causal, GQA.
// Pair-balanced: each wave processes q-tiles p and 127-p (equal work).
// K register double-buffer prefetch; V loads issued before softmax chain.
// grid (16, HQ, B), block 256 (4 indep waves).
// ---------------------------------------------------------------------------
__device__ __forceinline__ void load_ktile(short8 dst[8], const u16* kbase_lr, int j0) {
  const u16* kp = kbase_lr + (size_t)j0 * (HKV * DH);
#pragma unroll
  for (int s = 0; s < 4; ++s) {
    dst[s]     = *reinterpret_cast<const short8*>(kp + s * 32);
    dst[4 + s] = *reinterpret_cast<const short8*>(kp + (size_t)16 * (HKV * DH) + s * 32);
  }
}

__device__ __forceinline__ void attn_step(
    const short8 qf[4], const short8 kc[8], const u16* vbase,
    int j0, int q0, int lr, int lg, u16* pw,
    f32x4 O[8], float mrun[4], float lrun[4])
{
  f32x4 s0 = (f32x4){0.f, 0.f, 0.f, 0.f};
  f32x4 s1 = (f32x4){0.f, 0.f, 0.f, 0.f};
#pragma unroll
  for (int s = 0; s < 4; ++s) {
    s0 = __builtin_amdgcn_mfma_f32_16x16x32_bf16(qf[s], kc[s], s0, 0, 0, 0);
    s1 = __builtin_amdgcn_mfma_f32_16x16x32_bf16(qf[s], kc[4 + s], s1, 0, 0, 0);
  }
  // V loads issued here: latency hides under the softmax chain below
  short8 vv[8];
  const u16* vp = vbase + j0;
#pragma unroll
  for (int n = 0; n < 8; ++n)
    vv[n] = *reinterpret_cast<const short8*>(vp + (size_t)(n * 16 + lr) * L_);

  if (j0 + 31 > q0) {
    int key0 = j0 + lr;
#pragma unroll
    for (int r = 0; r < 4; ++r) {
      int q = q0 + lg * 4 + r;
      if (key0 > q)      s0[r] = -INFINITY;
      if (key0 + 16 > q) s1[r] = -INFINITY;
    }
  }
  float tmax[4];
#pragma unroll
  for (int r = 0; r < 4; ++r) tmax[r] = fmaxf(s0[r], s1[r]);
#pragma unroll
  for (int mm = 1; mm <= 8; mm <<= 1)
#pragma unroll
    for (int r = 0; r < 4; ++r) tmax[r] = fmaxf(tmax[r], __shfl_xor(tmax[r], mm));
  float corr[4];
#pragma unroll
  for (int r = 0; r < 4; ++r) {
    float mn = fmaxf(mrun[r], tmax[r]);
    corr[r] = __expf(mrun[r] - mn);
    mrun[r] = mn;
  }
  float p0[4], p1[4], rs[4];
#pragma unroll
  for (int r = 0; r < 4; ++r) {
    p0[r] = __expf(s0[r] - mrun[r]);
    p1[r] = __expf(s1[r] - mrun[r]);
    rs[r] = p0[r] + p1[r];
  }
#pragma unroll
  for (int mm = 1; mm <= 8; mm <<= 1)
#pragma unroll
    for (int r = 0; r < 4; ++r) rs[r] += __shfl_xor(rs[r], mm);
#pragma unroll
  for (int r = 0; r < 4; ++r) lrun[r] = lrun[r] * corr[r] + rs[r];
#pragma unroll
  for (int n = 0; n < 8; ++n)
#pragma unroll
    for (int r = 0; r < 4; ++r) O[n][r] *= corr[r];
#pragma unroll
  for (int r = 0; r < 4; ++r) {
    pw[(lg * 4 + r) * 40 + lr]      = f2bf(p0[r]);
    pw[(lg * 4 + r) * 40 + 16 + lr] = f2bf(p1[r]);
  }
  short8 pa = *reinterpret_cast<const short8*>(&pw[lr * 40 + lg * 8]);
#pragma unroll
  for (int n = 0; n < 8; ++n)
    O[n] = __builtin_amdgcn_mfma_f32_16x16x32_bf16(pa, vv[n], O[n], 0, 0, 0);
}

__device__ __forceinline__ void attn_tile(
    const u16* __restrict__ Qb, const u16* kbase_lr, const u16* vbase,
    u16* pw, u16* __restrict__ ab,
    int b, int h, int q0, int lr, int lg)
{
  const u16* qrow = Qb + ((size_t)(b * L_ + q0 + lr)) * (HQ * DH) + h * DH + lg * 8;
  short8 qf[4];
#pragma unroll
  for (int s = 0; s < 4; ++s)
    qf[s] = *reinterpret_cast<const short8*>(qrow + s * 32);

  f32x4 O[8];
#pragma unroll
  for (int n = 0; n < 8; ++n) O[n] = (f32x4){0.f, 0.f, 0.f, 0.f};
  float mrun[4] = {-INFINITY, -INFINITY, -INFINITY, -INFINITY};
  float lrun[4] = {0.f, 0.f, 0.f, 0.f};

  short8 ka[8], kb2[8];
  load_ktile(ka, kbase_lr, 0);
  const int jend = q0 + 16;
  int j0 = 0;
  while (true) {
    if (j0 + 32 < jend) load_ktile(kb2, kbase_lr, j0 + 32);
    attn_step(qf, ka, vbase, j0, q0, lr, lg, pw, O, mrun, lrun);
    j0 += 32; if (j0 >= jend) break;
    if (j0 + 32 < jend) load_ktile(ka, kbase_lr, j0 + 32);
    attn_step(qf, kb2, vbase, j0, q0, lr, lg, pw, O, mrun, lrun);
    j0 += 32; if (j0 >= jend) break;
  }

  float inv[4];
#pragma unroll
  for (int r = 0; r < 4; ++r) inv[r] = 1.0f / lrun[r];
  u16* obase = ab + (size_t)(b * L_ + q0) * (HQ * DH) + h * DH;
#pragma unroll
  for (int n = 0; n < 8; ++n)
#pragma unroll
    for (int r = 0; r < 4; ++r)
      obase[(size_t)(lg * 4 + r) * (HQ * DH) + n * 16 + lr] = f2bf(O[n][r] * inv[r]);
}

__global__ __launch_bounds__(256) void flash_attn_mfma_kernel(
    const u16* __restrict__ Qb, const u16* __restrict__ Kb,
    const u16* __restrict__ Vt, u16* __restrict__ ab)
{
  const int wave = threadIdx.x >> 6;
  const int lane = threadIdx.x & 63;
  const int p = blockIdx.x * 4 + wave;   // pair index 0..63
  const int h = blockIdx.y;
  const int b = blockIdx.z;
  const int kvh = h >> 3;
  const int lr = lane & 15;
  const int lg = lane >> 4;

  __shared__ u16 plds[4][16 * 40];
  u16* pw = plds[wave];

  const u16* kbase_lr = Kb + ((size_t)(b * L_ + lr)) * (HKV * DH) + kvh * DH + lg * 8;
  const u16* vbase = Vt + ((size_t)((b * HKV + kvh) * DH)) * L_ + lg * 8;

  attn_tile(Qb, kbase_lr, vbase, pw, ab, b, h, 16 * p, lr, lg);
  attn_tile(Qb, kbase_lr, vbase, pw, ab, b, h, 16 * (127 - p), lr, lg);
}

// ---------------------------------------------------------------------------
// launch
// ---------------------------------------------------------------------------
extern "C" void kernel_launch(void* const* d_in, const int* in_sizes, int n_in,
                              void* d_out, int out_size, void* d_ws, size_t ws_size,
                              hipStream_t stream) {
  const float* x  = (const float*)d_in[0];
  const float* wq = (const float*)d_in[1];
  const float* wk = (const float*)d_in[2];
  const float* wv = (const float*)d_in[3];
  const float* wo = (const float*)d_in[4];
  const float* bq = (const float*)d_in[5];
  const float* bk = (const float*)d_in[6];
  const float* bv = (const float*)d_in[7];
  float* out = (float*)d_out;

  const int M = B_ * L_;
  const int NQKV = HQ * DH + 2 * HKV * DH;  // 2560
  const size_t QN = (size_t)B_ * L_ * HQ * DH;
  const size_t KN = (size_t)B_ * L_ * HKV * DH;
  const size_t TN = (size_t)L_ * (DH / 2);

  float* ws = (float*)d_ws;
  float* qkvf = ws;
  float* ct   = qkvf + (size_t)M * NQKV;
  float* st   = ct + TN;
  float* bqkv = st + TN;
  u16* xb     = (u16*)(bqkv + 2560);
  u16* wqkvb  = xb + (size_t)M * E_;
  u16* Qbf    = wqkvb + (size_t)NQKV * E_;
  u16* Kbf    = Qbf + QN;
  u16* Vt     = Kbf + KN;
  u16* ab     = (u16*)qkvf;
  u16* wob    = Qbf;

  const float scale = 0.08838834764831845f;

  rope_tab_kernel<<<(L_ * (DH / 2) + 255) / 256, 256, 0, stream>>>(ct, st);

  cvt_bf16_kernel<<<(int)(QN / 8 / 256), 256, 0, stream>>>(x, xb, (int)QN);
  cvt_bf16_kernel<<<(HQ * DH * E_) / 8 / 256, 256, 0, stream>>>(wq, wqkvb, HQ * DH * E_);
  cvt_bf16_kernel<<<(HKV * DH * E_) / 8 / 256, 256, 0, stream>>>(
      wk, wqkvb + (size_t)(HQ * DH) * E_, HKV * DH * E_);
  cvt_bf16_kernel<<<(HKV * DH * E_) / 8 / 256, 256, 0, stream>>>(
      wv, wqkvb + (size_t)(HQ * DH + HKV * DH) * E_, HKV * DH * E_);

  hipMemcpyAsync(bqkv, bq, (size_t)HQ * DH * 4, hipMemcpyDeviceToDevice, stream);
  hipMemcpyAsync(bqkv + HQ * DH, bk, (size_t)HKV * DH * 4, hipMemcpyDeviceToDevice, stream);
  hipMemcpyAsync(bqkv + HQ * DH + HKV * DH, bv, (size_t)HKV * DH * 4, hipMemcpyDeviceToDevice, stream);

  gemm_bf16_kernel<<<dim3(NQKV / GBN, M / GBM), 256, 0, stream>>>(
      xb, wqkvb, bqkv, qkvf, M, NQKV, E_);

  {
    int totq = B_ * L_ * HQ * 64;
    rope_convert_kernel<<<(totq + 255) / 256, 256, 0, stream>>>(
        qkvf, Qbf, ct, st, HQ, NQKV, 0, scale, totq);
    int totk = B_ * L_ * HKV * 64;
    rope_convert_kernel<<<(totk + 255) / 256, 256, 0, stream>>>(
        qkvf, Kbf, ct, st, HKV, NQKV, HQ * DH, 1.0f, totk);
  }
  transpose_v_kernel<<<dim3(L_ / 64, DH / 64, B_ * HKV), 256, 0, stream>>>(
      qkvf, Vt, NQKV, HQ * DH + HKV * DH);

  flash_attn_mfma_kernel<<<dim3(16, HQ, B_), 256, 0, stream>>>(
      Qbf, Kbf, Vt, ab);

  cvt_bf16_kernel<<<(E_ * E_) / 8 / 256, 256, 0, stream>>>(wo, wob, E_ * E_);
  gemm_bf16_kernel<<<dim3(E_ / GBN, M / GBM), 256, 0, stream>>>(
      ab, wob, nullptr, out, M, E_, E_);
}

// Round 5
// 290.648 us; speedup vs baseline: 19.8588x; 1.3742x over previous
//
#include <hip/hip_runtime.h>
#include <math.h>

#define B_ 2
#define L_ 2048
#define E_ 2048
#define HQ 16
#define HKV 2
#define DH 128

typedef unsigned short u16;
typedef unsigned int u32;
typedef __attribute__((ext_vector_type(8))) short short8;
typedef __attribute__((ext_vector_type(4))) float f32x4;
typedef __attribute__((ext_vector_type(16))) float f32x16;
typedef __attribute__((ext_vector_type(4))) u32 u32x4;

static __device__ __forceinline__ u16 f2bf(float f) {
  unsigned int u = __float_as_uint(f);
  unsigned int r = (u + 0x7fffu + ((u >> 16) & 1u)) >> 16;
  return (u16)r;
}

static __device__ __forceinline__ u32 cvt_pk_bf16(float lo, float hi) {
  u32 r;
  asm volatile("v_cvt_pk_bf16_f32 %0, %1, %2" : "=v"(r) : "v"(lo), "v"(hi));
  return r;
}
// swaps D's upper-half lanes with S's lower-half lanes (gfx950)
static __device__ __forceinline__ void permswap(u32& a, u32& b) {
  asm volatile("v_permlane32_swap_b32 %0, %1" : "+v"(a), "+v"(b));
}

#define GLB(p) ((const __attribute__((address_space(1))) void*)(p))
#define LDS(p) ((__attribute__((address_space(3))) void*)(p))

// ---------------------------------------------------------------------------
// fp32 -> bf16 convert
// ---------------------------------------------------------------------------
__global__ void cvt_bf16_kernel(const float* __restrict__ in,
                                u16* __restrict__ out, int n) {
  int i = (blockIdx.x * 256 + threadIdx.x) * 8;
  if (i >= n) return;
  float4 a = *reinterpret_cast<const float4*>(in + i);
  float4 b = *reinterpret_cast<const float4*>(in + i + 4);
  short8 r;
  r[0] = (short)f2bf(a.x); r[1] = (short)f2bf(a.y);
  r[2] = (short)f2bf(a.z); r[3] = (short)f2bf(a.w);
  r[4] = (short)f2bf(b.x); r[5] = (short)f2bf(b.y);
  r[6] = (short)f2bf(b.z); r[7] = (short)f2bf(b.w);
  *reinterpret_cast<short8*>(out + i) = r;
}

// ---------------------------------------------------------------------------
// RoPE table
// ---------------------------------------------------------------------------
__global__ void rope_tab_kernel(float* __restrict__ ctab, float* __restrict__ stab) {
  int idx = blockIdx.x * 256 + threadIdx.x;
  if (idx >= L_ * (DH / 2)) return;
  int pos = idx >> 6;
  int f = idx & 63;
  float inv_freq = powf(10000.0f, -(float)f * (1.0f / 64.0f));
  float ang = (float)pos * inv_freq;
  float s, c;
  sincosf(ang, &s, &c);
  ctab[idx] = c;
  stab[idx] = s;
}

// ---------------------------------------------------------------------------
// RoPE apply + bf16 convert from fused qkv buffer
// ---------------------------------------------------------------------------
__global__ void rope_convert_kernel(const float* __restrict__ in,
                                    u16* __restrict__ outb,
                                    const float* __restrict__ ctab,
                                    const float* __restrict__ stab,
                                    int H, int rowStride, int colOff,
                                    float scale, int total) {
  int idx = blockIdx.x * 256 + threadIdx.x;
  if (idx >= total) return;
  int f = idx & 63;
  int row = idx >> 6;
  int h = row % H;
  int bl = row / H;
  int l = bl & (L_ - 1);
  size_t sbase = (size_t)bl * rowStride + colOff + (size_t)h * DH;
  size_t dbase = (size_t)bl * ((size_t)H * DH) + (size_t)h * DH;
  float x1 = in[sbase + f];
  float x2 = in[sbase + 64 + f];
  float c = ctab[l * 64 + f];
  float s = stab[l * 64 + f];
  outb[dbase + f]      = f2bf((x1 * c - x2 * s) * scale);
  outb[dbase + 64 + f] = f2bf((x2 * c + x1 * s) * scale);
}

// ---------------------------------------------------------------------------
// V transpose + bf16 convert: -> Vt[(b*HKV+kvh)*128+d][key]
// ---------------------------------------------------------------------------
__global__ __launch_bounds__(256) void transpose_v_kernel(
    const float* __restrict__ v, u16* __restrict__ Vt,
    int rowStride, int colOff) {
  __shared__ float tile[64][65];
  const int k0 = blockIdx.x * 64;
  const int d0 = blockIdx.y * 64;
  const int bk = blockIdx.z;
  const int b = bk / HKV, kvh = bk % HKV;
#pragma unroll
  for (int i = 0; i < 4; ++i) {
    int key = i * 16 + (threadIdx.x >> 4);
    int d4 = (threadIdx.x & 15) * 4;
    float4 vv = *reinterpret_cast<const float4*>(
        &v[(size_t)(b * L_ + k0 + key) * rowStride + colOff + kvh * DH + d0 + d4]);
    tile[key][d4 + 0] = vv.x; tile[key][d4 + 1] = vv.y;
    tile[key][d4 + 2] = vv.z; tile[key][d4 + 3] = vv.w;
  }
  __syncthreads();
  const int d = threadIdx.x >> 2;
  const int kq = (threadIdx.x & 3) * 16;
  u16* orow = Vt + ((size_t)(bk * DH + d0 + d)) * L_ + k0 + kq;
#pragma unroll
  for (int j = 0; j < 16; ++j) orow[j] = f2bf(tile[kq + j][d]);
}

// ---------------------------------------------------------------------------
// bf16 MFMA GEMM (m97 structure)
// ---------------------------------------------------------------------------
#define GBM 128
#define GBN 128
#define GBK 32

__global__ __launch_bounds__(256) void gemm_bf16_kernel(
    const u16* __restrict__ A, const u16* __restrict__ W,
    const float* __restrict__ bias, float* __restrict__ C,
    int M, int N, int K)
{
  __shared__ u16 As[GBM][GBK];
  __shared__ u16 Bs[GBN][GBK];
  const int tid = threadIdx.x;
  const int wave = tid >> 6;
  const int lane = tid & 63;
  const int lr = lane & 15;
  const int lg = lane >> 4;
  const int bm = blockIdx.y * GBM;
  const int bn = blockIdx.x * GBN;
  const int wm = (wave >> 1) * 64;
  const int wn = (wave & 1) * 64;

  const int srow = wave * 16 + (lane >> 2);
  const int scol = (lane & 3) * 8;
  const u16* ga = A + (size_t)(bm + srow) * K + scol;
  const u16* gb = W + (size_t)(bn + srow) * K + scol;
  u16* lA0 = &As[wave * 16][0];
  u16* lA1 = &As[64 + wave * 16][0];
  u16* lB0 = &Bs[wave * 16][0];
  u16* lB1 = &Bs[64 + wave * 16][0];

  f32x4 acc[4][4];
#pragma unroll
  for (int i = 0; i < 4; ++i)
#pragma unroll
    for (int j = 0; j < 4; ++j) acc[i][j] = (f32x4){0.f, 0.f, 0.f, 0.f};

  for (int k0 = 0; k0 < K; k0 += GBK) {
    __syncthreads();
    __builtin_amdgcn_global_load_lds(GLB(ga + k0), LDS(lA0), 16, 0, 0);
    __builtin_amdgcn_global_load_lds(GLB(ga + k0 + (size_t)64 * K), LDS(lA1), 16, 0, 0);
    __builtin_amdgcn_global_load_lds(GLB(gb + k0), LDS(lB0), 16, 0, 0);
    __builtin_amdgcn_global_load_lds(GLB(gb + k0 + (size_t)64 * K), LDS(lB1), 16, 0, 0);
    __syncthreads();

    short8 af[4], bf[4];
#pragma unroll
    for (int mi = 0; mi < 4; ++mi)
      af[mi] = *reinterpret_cast<const short8*>(&As[wm + mi * 16 + lr][lg * 8]);
#pragma unroll
    for (int ni = 0; ni < 4; ++ni)
      bf[ni] = *reinterpret_cast<const short8*>(&Bs[wn + ni * 16 + lr][lg * 8]);
#pragma unroll
    for (int mi = 0; mi < 4; ++mi)
#pragma unroll
      for (int ni = 0; ni < 4; ++ni)
        acc[mi][ni] = __builtin_amdgcn_mfma_f32_16x16x32_bf16(af[mi], bf[ni], acc[mi][ni], 0, 0, 0);
  }

#pragma unroll
  for (int ni = 0; ni < 4; ++ni) {
    int col = bn + wn + ni * 16 + lr;
    float bv = (bias != nullptr) ? bias[col] : 0.f;
#pragma unroll
    for (int mi = 0; mi < 4; ++mi) {
#pragma unroll
      for (int r = 0; r < 4; ++r) {
        int row = bm + wm + mi * 16 + lg * 4 + r;
        C[(size_t)row * N + col] = acc[mi][ni][r] + bv;
      }
    }
  }
}

// ---------------------------------------------------------------------------
// Flash attention, 32x32x16 MFMA, swapped QK^T => lane-local softmax.
// One wave per 32-row Q tile; pair-balanced (tiles p and 63-p).
// S^T = mfma(K, Q): lane holds 16 keys for query q = lane&31 (other 16 in
// partner lane q+32). P->A-frag via cvt_pk_bf16 + permlane32_swap (T12).
// Defer-max rescale (T13, THR=8); corr/l broadcasts via 32-float LDS.
// grid (32, HQ, B), block 64.
// ---------------------------------------------------------------------------
__device__ __forceinline__ void load_kt32(short8 dst[8], const u16* kbase, int j0) {
  const u16* kp = kbase + (size_t)j0 * (HKV * DH);
#pragma unroll
  for (int s = 0; s < 8; ++s)
    dst[s] = *reinterpret_cast<const short8*>(kp + s * 16);
}

__device__ __forceinline__ void attn_step32(
    const short8 qB[8], const short8 kc[8], const u16* vbase,
    int j0, int q0, int l5, int hi, float* cbuf,
    f32x16 O[4], float& mrun, float& lrun)
{
  // V loads for this step (8 x b128, hidden under QK + softmax)
  short8 vv[8];
  {
    const u16* vp = vbase + j0;
#pragma unroll
    for (int n = 0; n < 4; ++n) {
#pragma unroll
      for (int c = 0; c < 2; ++c)
        vv[n * 2 + c] = *reinterpret_cast<const short8*>(
            vp + (size_t)(n * 32) * L_ + c * 16);
    }
  }

  // S^T[key][q] accumulation, split into two dh-halves to shorten the chain
  f32x16 accl, acch;
#pragma unroll
  for (int r = 0; r < 16; ++r) { accl[r] = 0.f; acch[r] = 0.f; }
#pragma unroll
  for (int s = 0; s < 4; ++s)
    accl = __builtin_amdgcn_mfma_f32_32x32x16_bf16(kc[s], qB[s], accl, 0, 0, 0);
#pragma unroll
  for (int s = 4; s < 8; ++s)
    acch = __builtin_amdgcn_mfma_f32_32x32x16_bf16(kc[s], qB[s], acch, 0, 0, 0);

  float S[16];
#pragma unroll
  for (int r = 0; r < 16; ++r) S[r] = accl[r] + acch[r];

  // causal mask: only the diagonal step needs it
  if (j0 == q0) {
#pragma unroll
    for (int r = 0; r < 16; ++r) {
      int crow = (r & 3) + 8 * (r >> 2) + 4 * hi;
      if (crow > l5) S[r] = -INFINITY;
    }
  }

  // row max: in-register tree + one cross-half exchange
  float t8[8], t4[4], t2[2];
#pragma unroll
  for (int r = 0; r < 8; ++r) t8[r] = fmaxf(S[2 * r], S[2 * r + 1]);
#pragma unroll
  for (int r = 0; r < 4; ++r) t4[r] = fmaxf(t8[2 * r], t8[2 * r + 1]);
  t2[0] = fmaxf(t4[0], t4[1]); t2[1] = fmaxf(t4[2], t4[3]);
  float pmax = fmaxf(t2[0], t2[1]);
  pmax = fmaxf(pmax, __shfl_xor(pmax, 32));

  // defer-max: rescale O only when the max grew past the threshold
  if (__any(pmax > mrun + 8.0f)) {
    float mnew = fmaxf(mrun, pmax);
    float corr = __expf(mrun - mnew);
    mrun = mnew;
    lrun *= corr;
    if (hi == 0) cbuf[l5] = corr;
    float4 cr[4];
#pragma unroll
    for (int g = 0; g < 4; ++g)
      cr[g] = *reinterpret_cast<const float4*>(&cbuf[8 * g + 4 * hi]);
#pragma unroll
    for (int n = 0; n < 4; ++n)
#pragma unroll
      for (int r = 0; r < 16; ++r)
        O[n][r] *= (&cr[r >> 2].x)[r & 3];
  }

  // P = exp(S - m); row sum (tree + one exchange)
  float p[16];
#pragma unroll
  for (int r = 0; r < 16; ++r) p[r] = __expf(S[r] - mrun);
#pragma unroll
  for (int r = 0; r < 8; ++r) t8[r] = p[2 * r] + p[2 * r + 1];
#pragma unroll
  for (int r = 0; r < 4; ++r) t4[r] = t8[2 * r] + t8[2 * r + 1];
  t2[0] = t4[0] + t4[1]; t2[1] = t4[2] + t4[3];
  float rs = t2[0] + t2[1];
  rs += __shfl_xor(rs, 32);
  lrun += rs;

  // pack to bf16 pairs and redistribute into PV A-fragments (T12)
  u32 w[8];
#pragma unroll
  for (int t = 0; t < 8; ++t) w[t] = cvt_pk_bf16(p[2 * t], p[2 * t + 1]);
  permswap(w[0], w[2]); permswap(w[1], w[3]);
  permswap(w[4], w[6]); permswap(w[5], w[7]);
  short8 pa0 = __builtin_bit_cast(short8, (u32x4){w[0], w[1], w[2], w[3]});
  short8 pa1 = __builtin_bit_cast(short8, (u32x4){w[4], w[5], w[6], w[7]});

  // O += P V
#pragma unroll
  for (int n = 0; n < 4; ++n) {
    O[n] = __builtin_amdgcn_mfma_f32_32x32x16_bf16(pa0, vv[n * 2 + 0], O[n], 0, 0, 0);
    O[n] = __builtin_amdgcn_mfma_f32_32x32x16_bf16(pa1, vv[n * 2 + 1], O[n], 0, 0, 0);
  }
}

__device__ __forceinline__ void attn_tile32(
    const u16* __restrict__ Qb, const u16* kbase, const u16* vbase,
    float* cbuf, u16* __restrict__ ab,
    int b, int h, int q0, int l5, int hi)
{
  // Q as B-operand: qB[s][j] = Q[q0+l5][s*16 + hi*8 + j]
  const u16* qrow = Qb + ((size_t)(b * L_ + q0 + l5)) * (HQ * DH) + h * DH + hi * 8;
  short8 qB[8];
#pragma unroll
  for (int s = 0; s < 8; ++s)
    qB[s] = *reinterpret_cast<const short8*>(qrow + s * 16);

  f32x16 O[4];
#pragma unroll
  for (int n = 0; n < 4; ++n)
#pragma unroll
    for (int r = 0; r < 16; ++r) O[n][r] = 0.f;
  float mrun = -INFINITY, lrun = 0.f;

  const int nst = q0 / 32 + 1;
  short8 ka[8], kb2[8];
  load_kt32(ka, kbase, 0);
  int i = 0;
  while (true) {
    if (i + 1 < nst) load_kt32(kb2, kbase, (i + 1) * 32);
    attn_step32(qB, ka, vbase, i * 32, q0, l5, hi, cbuf, O, mrun, lrun);
    ++i; if (i >= nst) break;
    if (i + 1 < nst) load_kt32(ka, kbase, (i + 1) * 32);
    attn_step32(qB, kb2, vbase, i * 32, q0, l5, hi, cbuf, O, mrun, lrun);
    ++i; if (i >= nst) break;
  }

  // epilogue: broadcast l, divide, store bf16
  if (hi == 0) cbuf[l5] = lrun;
  float4 lv[4];
#pragma unroll
  for (int g = 0; g < 4; ++g)
    lv[g] = *reinterpret_cast<const float4*>(&cbuf[8 * g + 4 * hi]);

  u16* obase = ab + (size_t)(b * L_ + q0) * (HQ * DH) + h * DH;
#pragma unroll
  for (int r = 0; r < 16; ++r) {
    int crow = (r & 3) + 8 * (r >> 2) + 4 * hi;
    float inv = __builtin_amdgcn_rcpf((&lv[r >> 2].x)[r & 3]);
    u16* orow = obase + (size_t)crow * (HQ * DH) + l5;
#pragma unroll
    for (int n = 0; n < 4; ++n)
      orow[n * 32] = f2bf(O[n][r] * inv);
  }
}

__global__ __launch_bounds__(64, 1) void flash_attn_mfma32_kernel(
    const u16* __restrict__ Qb, const u16* __restrict__ Kb,
    const u16* __restrict__ Vt, u16* __restrict__ ab)
{
  const int lane = threadIdx.x & 63;
  const int l5 = lane & 31;
  const int hi = lane >> 5;
  const int p = blockIdx.x;          // pair index 0..31
  const int h = blockIdx.y;
  const int b = blockIdx.z;
  const int kvh = h >> 3;            // G = 8

  __shared__ __align__(16) float cbuf[32];

  // K as A-operand: row = key = j0 + l5, k = s*16 + hi*8 + j
  const u16* kbase = Kb + ((size_t)(b * L_ + l5)) * (HKV * DH) + kvh * DH + hi * 8;
  // V as B-operand from Vt[dh][key]: row = n*32 + l5, key = j0 + c*16 + hi*8 + j
  const u16* vbase = Vt + ((size_t)((b * HKV + kvh) * DH + l5)) * L_ + hi * 8;

  attn_tile32(Qb, kbase, vbase, cbuf, ab, b, h, 32 * p, l5, hi);
  attn_tile32(Qb, kbase, vbase, cbuf, ab, b, h, 32 * (63 - p), l5, hi);
}

// ---------------------------------------------------------------------------
// launch
// ---------------------------------------------------------------------------
extern "C" void kernel_launch(void* const* d_in, const int* in_sizes, int n_in,
                              void* d_out, int out_size, void* d_ws, size_t ws_size,
                              hipStream_t stream) {
  const float* x  = (const float*)d_in[0];
  const float* wq = (const float*)d_in[1];
  const float* wk = (const float*)d_in[2];
  const float* wv = (const float*)d_in[3];
  const float* wo = (const float*)d_in[4];
  const float* bq = (const float*)d_in[5];
  const float* bk = (const float*)d_in[6];
  const float* bv = (const float*)d_in[7];
  float* out = (float*)d_out;

  const int M = B_ * L_;
  const int NQKV = HQ * DH + 2 * HKV * DH;  // 2560
  const size_t QN = (size_t)B_ * L_ * HQ * DH;
  const size_t KN = (size_t)B_ * L_ * HKV * DH;
  const size_t TN = (size_t)L_ * (DH / 2);

  float* ws = (float*)d_ws;
  float* qkvf = ws;
  float* ct   = qkvf + (size_t)M * NQKV;
  float* st   = ct + TN;
  float* bqkv = st + TN;
  u16* xb     = (u16*)(bqkv + 2560);
  u16* wqkvb  = xb + (size_t)M * E_;
  u16* Qbf    = wqkvb + (size_t)NQKV * E_;
  u16* Kbf    = Qbf + QN;
  u16* Vt     = Kbf + KN;
  u16* ab     = (u16*)qkvf;   // alias: qkvf dead after rope/transpose
  u16* wob    = Qbf;          // alias: Qbf dead after attention

  const float scale = 0.08838834764831845f;

  rope_tab_kernel<<<(L_ * (DH / 2) + 255) / 256, 256, 0, stream>>>(ct, st);

  cvt_bf16_kernel<<<(int)(QN / 8 / 256), 256, 0, stream>>>(x, xb, (int)QN);
  cvt_bf16_kernel<<<(HQ * DH * E_) / 8 / 256, 256, 0, stream>>>(wq, wqkvb, HQ * DH * E_);
  cvt_bf16_kernel<<<(HKV * DH * E_) / 8 / 256, 256, 0, stream>>>(
      wk, wqkvb + (size_t)(HQ * DH) * E_, HKV * DH * E_);
  cvt_bf16_kernel<<<(HKV * DH * E_) / 8 / 256, 256, 0, stream>>>(
      wv, wqkvb + (size_t)(HQ * DH + HKV * DH) * E_, HKV * DH * E_);

  hipMemcpyAsync(bqkv, bq, (size_t)HQ * DH * 4, hipMemcpyDeviceToDevice, stream);
  hipMemcpyAsync(bqkv + HQ * DH, bk, (size_t)HKV * DH * 4, hipMemcpyDeviceToDevice, stream);
  hipMemcpyAsync(bqkv + HQ * DH + HKV * DH, bv, (size_t)HKV * DH * 4, hipMemcpyDeviceToDevice, stream);

  gemm_bf16_kernel<<<dim3(NQKV / GBN, M / GBM), 256, 0, stream>>>(
      xb, wqkvb, bqkv, qkvf, M, NQKV, E_);

  {
    int totq = B_ * L_ * HQ * 64;
    rope_convert_kernel<<<(totq + 255) / 256, 256, 0, stream>>>(
        qkvf, Qbf, ct, st, HQ, NQKV, 0, scale, totq);
    int totk = B_ * L_ * HKV * 64;
    rope_convert_kernel<<<(totk + 255) / 256, 256, 0, stream>>>(
        qkvf, Kbf, ct, st, HKV, NQKV, HQ * DH, 1.0f, totk);
  }
  transpose_v_kernel<<<dim3(L_ / 64, DH / 64, B_ * HKV), 256, 0, stream>>>(
      qkvf, Vt, NQKV, HQ * DH + HKV * DH);

  flash_attn_mfma32_kernel<<<dim3(32, HQ, B_), 64, 0, stream>>>(
      Qbf, Kbf, Vt, ab);

  cvt_bf16_kernel<<<(E_ * E_) / 8 / 256, 256, 0, stream>>>(wo, wob, E_ * E_);
  gemm_bf16_kernel<<<dim3(E_ / GBN, M / GBM), 256, 0, stream>>>(
      ab, wob, nullptr, out, M, E_, E_);
}